// Round 1
// 422.282 us; speedup vs baseline: 1.0198x; 1.0198x over previous
//
#include <hip/hip_runtime.h>

// FWHT over 2^14 elements per row, 4096 rows, scale 2^-7.
// One block (512 threads = 8 waves) per row. 32 elements/thread as 8 float4s.
//
// Stage plan (14 total; butterflies on distinct bits commute):
//   - load-time register stages: bits e0,e1 (inside float4) + e11,e12,e13
//     (across the 8 float4s j)                              -> 5 stages
//   - LDS phase A: slot bits F[2:0] (= e[4:2])              -> 3 stages
//   - LDS phase B: slot bits F[5:3] (= e[7:5])              -> 3 stages
//   - LDS phase C: slot bits F[8:6] (= e[10:8])             -> 3 stages
//
// KEY STRUCTURAL FACT (this revision): after the stage-in scatter, wave w's
// phases A/B/C touch ONLY slots [512w, 512w+512) — the scatter put all
// elements with e[13:11]==w into region w, and every later gather stays
// inside that region. So only ONE __syncthreads (after the scatter) is
// needed; the old A->B and B->C barriers forced 8-wave lockstep for no
// correctness reason and are removed. In-wave ds_write->ds_read ordering is
// guaranteed by the compiler's lgkmcnt waits (same-wave DS ops complete in
// order).
//
// Swizzle: slot^((slot>>3)&7), algebraically folded per phase into a
// per-thread constant XOR (no per-access shift/and/xor chains):
//   stage-in: swz(tid+512j)          = (tid ^ ((tid>>3)&7)) + 512j
//   phase A:  swz(8*lane+512w + g)   = base + (g ^ (lane&7))
//   phase B:  swz(b2 + 8g + (tid&7)) = b2 + 8g + ((tid&7) ^ g)
//   phase C:  swz(lane+512w + 64g)   = ((lane ^ (lane>>3)) + 512w) + 64g
// Every wave64 b128 access lands 8 lanes per 4-bank group: conflict-free.
//
// Both streams are single-use (read-once input, write-once output):
// nontemporal loads/stores keep 512 MiB from churning L2/LLC.

#define NF4 4096          // float4 slots per row (16384 floats)
#define SCALE 0.0078125f  // 2^-7

typedef float f4 __attribute__((ext_vector_type(4)));

__device__ __forceinline__ void bfly2(f4& a, f4& b) {
    f4 t = a;
    a = t + b;
    b = t - b;
}

// 3 butterfly stages across the 8-element register index
__device__ __forceinline__ void bfly8(f4 v[8]) {
    bfly2(v[0], v[1]); bfly2(v[2], v[3]); bfly2(v[4], v[5]); bfly2(v[6], v[7]);
    bfly2(v[0], v[2]); bfly2(v[1], v[3]); bfly2(v[4], v[6]); bfly2(v[5], v[7]);
    bfly2(v[0], v[4]); bfly2(v[1], v[5]); bfly2(v[2], v[6]); bfly2(v[3], v[7]);
}

// 2 butterfly stages inside a float4 (bits e0, e1)
__device__ __forceinline__ void bfly_inner(f4& t) {
    float a = t.x + t.y, b = t.x - t.y;
    float c = t.z + t.w, d = t.z - t.w;
    t.x = a + c; t.y = b + d; t.z = a - c; t.w = b - d;
}

__global__ __launch_bounds__(512)
void fwht_kernel(const float* __restrict__ in, float* __restrict__ out) {
    __shared__ f4 lds[NF4];

    const int tid  = threadIdx.x;
    const int lane = tid & 63;
    const int w    = tid >> 6;

    const f4* in4  = (const f4*)in  + (size_t)blockIdx.x * NF4;
    f4*       out4 = (f4*)out       + (size_t)blockIdx.x * NF4;

    f4 v[8];

    // ---- load (coalesced: per j, lanes contiguous) + 5 register stages
#pragma unroll
    for (int j = 0; j < 8; ++j)
        v[j] = __builtin_nontemporal_load(in4 + tid + 512 * j);
#pragma unroll
    for (int j = 0; j < 8; ++j) bfly_inner(v[j]);   // e0, e1
    bfly8(v);                                       // e11, e12, e13

    // ---- stage-in scatter (the ONLY cross-wave exchange)
    const int st = tid ^ ((tid >> 3) & 7);
#pragma unroll
    for (int j = 0; j < 8; ++j) lds[st + 512 * j] = v[j];
    __syncthreads();   // the only block-wide dependency in the kernel

    // ---- phase A: slots 512w + 8*lane + g   (gather e[4:2])
    {
        const int s    = lane & 7;
        const int base = 8 * lane + 512 * w;
#pragma unroll
        for (int g = 0; g < 8; ++g) v[g] = lds[base + (g ^ s)];
        bfly8(v);
#pragma unroll
        for (int g = 0; g < 8; ++g) lds[base + (g ^ s)] = v[g];
    }

    // ---- phase B: slots 512w + 64*lane[5:3] + 8g + lane[2:0]  (gather e[7:5])
    //      wave-private region: no barrier needed
    {
        const int c  = tid & 7;
        const int b2 = 64 * ((lane >> 3) & 7) + 512 * w;
#pragma unroll
        for (int g = 0; g < 8; ++g) v[g] = lds[b2 + 8 * g + (c ^ g)];
        bfly8(v);
#pragma unroll
        for (int g = 0; g < 8; ++g) lds[b2 + 8 * g + (c ^ g)] = v[g];
    }

    // ---- phase C: slots 512w + lane + 64g  (gather e[10:8]), scale, store
    //      wave-private region: no barrier needed
    {
        const int s2 = (lane >> 3) & 7;
        const int rb = (lane ^ s2) + 512 * w;   // swizzled read base
        const int sb = lane + 512 * w;          // unswizzled store base
#pragma unroll
        for (int g = 0; g < 8; ++g) v[g] = lds[rb + 64 * g];
        bfly8(v);
#pragma unroll
        for (int g = 0; g < 8; ++g)
            __builtin_nontemporal_store(v[g] * SCALE, out4 + sb + 64 * g);
    }
}

extern "C" void kernel_launch(void* const* d_in, const int* in_sizes, int n_in,
                              void* d_out, int out_size, void* d_ws, size_t ws_size,
                              hipStream_t stream) {
    const float* phi = (const float*)d_in[0];
    float* out = (float*)d_out;
    // 4096 rows, one block per row
    fwht_kernel<<<4096, 512, 0, stream>>>(phi, out);
}